// Round 1
// baseline (104.655 us; speedup 1.0000x reference)
//
#include <hip/hip_runtime.h>

namespace {

constexpr int Hh   = 256;
constexpr int Ww   = 256;
constexpr int IMG  = Hh * Ww;            // 65536
constexpr int NV   = (Hh - 1) * Ww;      // 65280 vertical candidates
constexpr int NC   = NV + Hh * (Ww - 1); // 130560 total candidates
constexpr int PMAX = 8192;
constexpr int CB   = 256;                // candidate block
constexpr int NCB  = (NC + CB - 1) / CB; // 510
constexpr int NB   = 4;                  // batch
constexpr int NIMG = 2 * NB;             // 8 images (pred 0..3, gt 4..7)
constexpr float EPSF = 1e-8f;
constexpr int TILE = 2048;               // chamfer LDS tile (16 KB)

// Candidate c -> (point, valid). Order matches reference: vertical block
// (row-major over (H-1)xW) then horizontal block (row-major over Hx(W-1)).
__device__ inline bool cand_pt(const float* img, int c, float2& pt) {
  if (c < NV) {
    int i = c >> 8, j = c & 255;             // W == 256
    float v1 = img[i * Ww + j];
    float v2 = img[(i + 1) * Ww + j];
    bool valid = (v1 == 0.f) | (v2 == 0.f) | (v1 * v2 < 0.f);
    float a = fabsf(v1) / (fabsf(v1) + fabsf(v2) + EPSF);
    float row = (v1 == 0.f) ? (float)i
              : ((v2 == 0.f) ? (float)(i + 1) : (float)i + a);
    pt.x = row; pt.y = (float)j;
    return valid;
  } else {
    int cc = c - NV;
    int i = cc / (Ww - 1);
    int j = cc - i * (Ww - 1);
    float h1 = img[i * Ww + j];
    float h2 = img[i * Ww + j + 1];
    bool valid = (h1 == 0.f) | (h2 == 0.f) | (h1 * h2 < 0.f);
    float a = fabsf(h1) / (fabsf(h1) + fabsf(h2) + EPSF);
    float col = (h1 == 0.f) ? (float)j
              : ((h2 == 0.f) ? (float)(j + 1) : (float)j + a);
    pt.x = (float)i; pt.y = col;
    return valid;
  }
}

__device__ inline const float* img_ptr(const float* pred, const float* gt, int img) {
  return (img < NB) ? pred + img * IMG : gt + (img - NB) * IMG;
}

// Phase A: per-block valid counts.
__global__ void count_kernel(const float* __restrict__ pred,
                             const float* __restrict__ gt,
                             int* __restrict__ bCounts) {
  int img = blockIdx.y;
  const float* im = img_ptr(pred, gt, img);
  int c = blockIdx.x * CB + threadIdx.x;
  bool valid = false;
  float2 pt;
  if (c < NC) valid = cand_pt(im, c, pt);
  unsigned long long b = __ballot(valid);
  __shared__ int wc[CB / 64];
  int lane = threadIdx.x & 63, wid = threadIdx.x >> 6;
  if (lane == 0) wc[wid] = __popcll(b);
  __syncthreads();
  if (threadIdx.x == 0) {
    int s = 0;
    for (int w = 0; w < CB / 64; ++w) s += wc[w];
    bCounts[img * NCB + blockIdx.x] = s;
  }
}

// Phase B: per-image exclusive scan of the 510 block counts (one block/image).
__global__ void scan_kernel(const int* __restrict__ bCounts,
                            int* __restrict__ bOffs,
                            int* __restrict__ counts) {
  int img = blockIdx.x;
  __shared__ int s[512];
  int t = threadIdx.x;
  int v = (t < NCB) ? bCounts[img * NCB + t] : 0;
  s[t] = v;
  __syncthreads();
  for (int off = 1; off < 512; off <<= 1) {
    int x = s[t];
    int y = (t >= off) ? s[t - off] : 0;
    __syncthreads();
    s[t] = x + y;
    __syncthreads();
  }
  if (t < NCB) bOffs[img * NCB + t] = s[t] - v;   // exclusive prefix
  if (t == 511) counts[img] = min(s[511], PMAX);  // n = min(valid, 8192)
}

// Phase C: order-preserving compaction into pts[img][rank], rank < PMAX.
__global__ void write_kernel(const float* __restrict__ pred,
                             const float* __restrict__ gt,
                             const int* __restrict__ bOffs,
                             float2* __restrict__ pts) {
  int img = blockIdx.y;
  const float* im = img_ptr(pred, gt, img);
  int c = blockIdx.x * CB + threadIdx.x;
  bool valid = false;
  float2 pt;
  if (c < NC) valid = cand_pt(im, c, pt);
  unsigned long long b = __ballot(valid);
  __shared__ int wofs[CB / 64];
  int lane = threadIdx.x & 63, wid = threadIdx.x >> 6;
  if (lane == 0) wofs[wid] = __popcll(b);
  __syncthreads();
  if (threadIdx.x == 0) {
    int run = 0;
    for (int w = 0; w < CB / 64; ++w) { int t = wofs[w]; wofs[w] = run; run += t; }
  }
  __syncthreads();
  if (valid) {
    int rank = bOffs[img * NCB + blockIdx.x] + wofs[wid]
             + __popcll(b & ((1ull << lane) - 1ull));
    if (rank < PMAX) pts[img * PMAX + rank] = pt;
  }
}

// Phase D: chamfer. grid = (PMAX/256, 2 dirs, B samples).
// dir 0: queries=pred[b], targets=gt[b]  -> sums[0*NB+b] (for mean1)
// dir 1: queries=gt[b],   targets=pred[b]-> sums[1*NB+b] (for mean2)
__global__ void chamfer_kernel(const float2* __restrict__ pts,
                               const int* __restrict__ counts,
                               float* __restrict__ sums) {
  int b   = blockIdx.z;
  int dir = blockIdx.y;
  int qimg = (dir == 0) ? b : NB + b;
  int timg = (dir == 0) ? NB + b : b;
  int nq = counts[qimg], nt = counts[timg];
  if (nq == 0 || nt == 0) return;                 // block-uniform
  if ((int)(blockIdx.x * blockDim.x) >= nq) return;

  __shared__ float2 tgt[TILE];
  int q = blockIdx.x * blockDim.x + threadIdx.x;
  float2 p = (q < nq) ? pts[qimg * PMAX + q] : make_float2(0.f, 0.f);
  float m = 3.4e38f;

  for (int ts = 0; ts < nt; ts += TILE) {
    int cnt = min(TILE, nt - ts);
    for (int t = threadIdx.x; t < cnt; t += blockDim.x)
      tgt[t] = pts[timg * PMAX + ts + t];
    __syncthreads();
    for (int j = 0; j < cnt; ++j) {               // LDS broadcast reads
      float dx = p.x - tgt[j].x;
      float dy = p.y - tgt[j].y;
      float d2 = dx * dx + dy * dy;
      m = fminf(m, d2);
    }
    __syncthreads();
  }

  float val = (q < nq) ? sqrtf(m) : 0.f;
  for (int off = 32; off > 0; off >>= 1) val += __shfl_down(val, off, 64);
  __shared__ float wsum[4];
  int lane = threadIdx.x & 63, wid = threadIdx.x >> 6;
  if (lane == 0) wsum[wid] = val;
  __syncthreads();
  if (threadIdx.x == 0)
    atomicAdd(&sums[dir * NB + b], wsum[0] + wsum[1] + wsum[2] + wsum[3]);
}

// Phase E: per-sample sum |pred - gt| with float4 loads.
__global__ void l1_kernel(const float* __restrict__ pred,
                          const float* __restrict__ gt,
                          float* __restrict__ sdfsums) {
  int b = blockIdx.y;
  int idx = blockIdx.x * blockDim.x + threadIdx.x;   // over IMG/4 float4s
  const float4* p4 = (const float4*)(pred + b * IMG);
  const float4* g4 = (const float4*)(gt + b * IMG);
  float4 p = p4[idx], g = g4[idx];
  float v = fabsf(p.x - g.x) + fabsf(p.y - g.y)
          + fabsf(p.z - g.z) + fabsf(p.w - g.w);
  for (int off = 32; off > 0; off >>= 1) v += __shfl_down(v, off, 64);
  __shared__ float wsum[4];
  int lane = threadIdx.x & 63, wid = threadIdx.x >> 6;
  if (lane == 0) wsum[wid] = v;
  __syncthreads();
  if (threadIdx.x == 0)
    atomicAdd(&sdfsums[b], wsum[0] + wsum[1] + wsum[2] + wsum[3]);
}

// Phase F: combine to the scalar loss.
__global__ void final_kernel(const int* __restrict__ counts,
                             const float* __restrict__ sums,
                             const float* __restrict__ sdfsums,
                             float* __restrict__ out) {
  if (threadIdx.x == 0 && blockIdx.x == 0) {
    float total = 0.f;
    for (int b = 0; b < NB; ++b) {
      float n1 = (float)counts[b];
      float n2 = (float)counts[NB + b];
      float mean1 = sums[b]      / fmaxf(n1, 1.f);
      float mean2 = sums[NB + b] / fmaxf(n2, 1.f);
      float cd = -mean1 + mean2;
      float ch = (n1 > 0.f && n2 > 0.f) ? fabsf(cd) : 0.f;
      total += ch + sdfsums[b] * (1.f / (float)IMG);
    }
    out[0] = total * (1.f / (float)NB);
  }
}

} // namespace

extern "C" void kernel_launch(void* const* d_in, const int* in_sizes, int n_in,
                              void* d_out, int out_size, void* d_ws, size_t ws_size,
                              hipStream_t stream) {
  const float* pred = (const float*)d_in[0];
  const float* gt   = (const float*)d_in[1];
  float* out = (float*)d_out;

  char* ws = (char*)d_ws;
  // layout (bytes):
  //   [0,32)      float sums[8]        (atomic accum, zeroed each call)
  //   [32,48)     float sdfsums[4]     (atomic accum, zeroed each call)
  //   [64,96)     int counts[8]
  //   [128, +16320)          int bCounts[8*510]
  //   [16448, +16320)        int bOffs[8*510]
  //   [32768, +524288)       float2 pts[8*8192]
  float*  sums    = (float*)(ws + 0);
  float*  sdfsums = (float*)(ws + 32);
  int*    counts  = (int*)(ws + 64);
  int*    bCounts = (int*)(ws + 128);
  int*    bOffs   = (int*)(ws + 16448);
  float2* pts     = (float2*)(ws + 32768);

  hipMemsetAsync(ws, 0, 48, stream);  // zero sums + sdfsums

  dim3 gc(NCB, NIMG);
  count_kernel<<<gc, CB, 0, stream>>>(pred, gt, bCounts);
  scan_kernel<<<NIMG, 512, 0, stream>>>(bCounts, bOffs, counts);
  write_kernel<<<gc, CB, 0, stream>>>(pred, gt, bOffs, pts);
  chamfer_kernel<<<dim3(PMAX / 256, 2, NB), 256, 0, stream>>>(pts, counts, sums);
  l1_kernel<<<dim3(IMG / 4 / 256, NB), 256, 0, stream>>>(pred, gt, sdfsums);
  final_kernel<<<1, 1, 0, stream>>>(counts, sums, sdfsums, out);
}

// Round 2
// 48.330 us; speedup vs baseline: 2.1654x; 2.1654x over previous
//
#include <hip/hip_runtime.h>

namespace {

constexpr int Hh   = 256;
constexpr int Ww   = 256;
constexpr int IMG  = Hh * Ww;            // 65536
constexpr int NV   = (Hh - 1) * Ww;      // 65280 vertical candidates
constexpr int NC   = NV + Hh * (Ww - 1); // 130560 total candidates
constexpr int PMAX = 8192;
constexpr int CB   = 256;                // candidate block
constexpr int NCB  = (NC + CB - 1) / CB; // 510
constexpr int NB   = 4;                  // batch
constexpr int NIMG = 2 * NB;             // 8 images (pred 0..3, gt 4..7)
constexpr float EPSF = 1e-8f;
constexpr int TCH  = 8;                  // chamfer target chunks
constexpr int CHK  = PMAX / TCH;         // 1024 max targets per chunk (8 KB LDS)

// Candidate c -> (point, valid). Order matches reference: vertical block
// (row-major over (H-1)xW) then horizontal block (row-major over Hx(W-1)).
__device__ inline bool cand_pt(const float* img, int c, float2& pt) {
  if (c < NV) {
    int i = c >> 8, j = c & 255;             // W == 256
    float v1 = img[i * Ww + j];
    float v2 = img[(i + 1) * Ww + j];
    bool valid = (v1 == 0.f) | (v2 == 0.f) | (v1 * v2 < 0.f);
    float a = fabsf(v1) / (fabsf(v1) + fabsf(v2) + EPSF);
    float row = (v1 == 0.f) ? (float)i
              : ((v2 == 0.f) ? (float)(i + 1) : (float)i + a);
    pt.x = row; pt.y = (float)j;
    return valid;
  } else {
    int cc = c - NV;
    int i = cc / (Ww - 1);
    int j = cc - i * (Ww - 1);
    float h1 = img[i * Ww + j];
    float h2 = img[i * Ww + j + 1];
    bool valid = (h1 == 0.f) | (h2 == 0.f) | (h1 * h2 < 0.f);
    float a = fabsf(h1) / (fabsf(h1) + fabsf(h2) + EPSF);
    float col = (h1 == 0.f) ? (float)j
              : ((h2 == 0.f) ? (float)(j + 1) : (float)j + a);
    pt.x = (float)i; pt.y = col;
    return valid;
  }
}

__device__ inline const float* img_ptr(const float* pred, const float* gt, int img) {
  return (img < NB) ? pred + img * IMG : gt + (img - NB) * IMG;
}

// Phase A: per-block valid counts, with the L1 |pred-gt| sum fused in
// (candidate index doubles as pixel index for c < IMG, img < NB).
__global__ void count_kernel(const float* __restrict__ pred,
                             const float* __restrict__ gt,
                             int* __restrict__ bCounts,
                             float* __restrict__ sdfsums) {
  int img = blockIdx.y;
  const float* im = img_ptr(pred, gt, img);
  int c = blockIdx.x * CB + threadIdx.x;
  bool valid = false;
  float2 pt;
  if (c < NC) valid = cand_pt(im, c, pt);
  unsigned long long b = __ballot(valid);
  __shared__ float wred[CB / 64];
  int lane = threadIdx.x & 63, wid = threadIdx.x >> 6;
  if (lane == 0) wred[wid] = (float)__popcll(b);
  __syncthreads();
  if (threadIdx.x == 0) {
    int s = 0;
    for (int w = 0; w < CB / 64; ++w) s += (int)wred[w];
    bCounts[img * NCB + blockIdx.x] = s;
  }

  // fused L1 (pred images only; pixel blocks only)
  if (img < NB && blockIdx.x * CB < IMG) {
    __syncthreads();
    float v = 0.f;
    if (c < IMG) v = fabsf(pred[img * IMG + c] - gt[img * IMG + c]);
    for (int off = 32; off > 0; off >>= 1) v += __shfl_down(v, off, 64);
    if (lane == 0) wred[wid] = v;
    __syncthreads();
    if (threadIdx.x == 0)
      atomicAdd(&sdfsums[img], wred[0] + wred[1] + wred[2] + wred[3]);
  }
}

// Phase B: per-image exclusive scan of the 510 block counts (one block/image).
__global__ void scan_kernel(const int* __restrict__ bCounts,
                            int* __restrict__ bOffs,
                            int* __restrict__ counts) {
  int img = blockIdx.x;
  __shared__ int s[512];
  int t = threadIdx.x;
  int v = (t < NCB) ? bCounts[img * NCB + t] : 0;
  s[t] = v;
  __syncthreads();
  for (int off = 1; off < 512; off <<= 1) {
    int x = s[t];
    int y = (t >= off) ? s[t - off] : 0;
    __syncthreads();
    s[t] = x + y;
    __syncthreads();
  }
  if (t < NCB) bOffs[img * NCB + t] = s[t] - v;   // exclusive prefix
  if (t == 511) counts[img] = min(s[511], PMAX);  // n = min(valid, 8192)
}

// Phase C: order-preserving compaction into pts[img][rank], rank < PMAX.
__global__ void write_kernel(const float* __restrict__ pred,
                             const float* __restrict__ gt,
                             const int* __restrict__ bOffs,
                             float2* __restrict__ pts) {
  int img = blockIdx.y;
  const float* im = img_ptr(pred, gt, img);
  int c = blockIdx.x * CB + threadIdx.x;
  bool valid = false;
  float2 pt;
  if (c < NC) valid = cand_pt(im, c, pt);
  unsigned long long b = __ballot(valid);
  __shared__ int wofs[CB / 64];
  int lane = threadIdx.x & 63, wid = threadIdx.x >> 6;
  if (lane == 0) wofs[wid] = __popcll(b);
  __syncthreads();
  if (threadIdx.x == 0) {
    int run = 0;
    for (int w = 0; w < CB / 64; ++w) { int t = wofs[w]; wofs[w] = run; run += t; }
  }
  __syncthreads();
  if (valid) {
    int rank = bOffs[img * NCB + blockIdx.x] + wofs[wid]
             + __popcll(b & ((1ull << lane) - 1ull));
    if (rank < PMAX) pts[img * PMAX + rank] = pt;
  }
}

__device__ inline void min_step(float2 p, float2 t, float& m) {
  float dx = p.x - t.x;
  float dy = p.y - t.y;
  m = fminf(m, dx * dx + dy * dy);
}

// Phase D: partial chamfer. grid = (PMAX/256 qblocks, TCH tchunks, 2*NB).
// Each block: partial min^2 over its target chunk for its 256 queries,
// merged via uint atomicMin (valid: d2 >= 0 so IEEE bits are monotone).
__global__ void chamfer_kernel(const float2* __restrict__ pts,
                               const int* __restrict__ counts,
                               unsigned int* __restrict__ minq) {
  int b   = blockIdx.z & (NB - 1);
  int dir = blockIdx.z / NB;
  int qimg = (dir == 0) ? b : NB + b;
  int timg = (dir == 0) ? NB + b : b;
  int nq = counts[qimg], nt = counts[timg];
  if (nq == 0 || nt == 0) return;                  // block-uniform
  int qbase = blockIdx.x * 256;
  if (qbase >= nq) return;
  int len = (nt + TCH - 1) / TCH;
  int ts  = blockIdx.y * len;
  if (ts >= nt) return;
  int cnt = min(len, nt - ts);

  __shared__ float2 tgt[CHK];
  for (int t = threadIdx.x; t < cnt; t += 256)
    tgt[t] = pts[timg * PMAX + ts + t];
  __syncthreads();

  int q = qbase + threadIdx.x;
  float2 p = (q < nq) ? pts[qimg * PMAX + q] : make_float2(0.f, 0.f);
  float m0 = 3.4e38f, m1 = 3.4e38f, m2 = 3.4e38f, m3 = 3.4e38f;
  int j = 0;
  for (; j + 4 <= cnt; j += 4) {                   // 4 independent min chains
    min_step(p, tgt[j + 0], m0);
    min_step(p, tgt[j + 1], m1);
    min_step(p, tgt[j + 2], m2);
    min_step(p, tgt[j + 3], m3);
  }
  for (; j < cnt; ++j) min_step(p, tgt[j], m0);
  float m = fminf(fminf(m0, m1), fminf(m2, m3));

  if (q < nq)
    atomicMin(&minq[(dir * NB + b) * PMAX + q], __float_as_uint(m));
}

// Phase E: per-(dir,b) sum of sqrt(min^2) -> sums[dir*NB+b].
__global__ void reduce_kernel(const unsigned int* __restrict__ minq,
                              const int* __restrict__ counts,
                              float* __restrict__ sums) {
  int combo = blockIdx.x;                 // dir*NB + b
  int dir = combo / NB, b = combo & (NB - 1);
  int qimg = (dir == 0) ? b : NB + b;
  int nq = counts[qimg];
  float s = 0.f;
  for (int q = threadIdx.x; q < nq; q += 256)
    s += sqrtf(__uint_as_float(minq[combo * PMAX + q]));
  for (int off = 32; off > 0; off >>= 1) s += __shfl_down(s, off, 64);
  __shared__ float wsum[4];
  int lane = threadIdx.x & 63, wid = threadIdx.x >> 6;
  if (lane == 0) wsum[wid] = s;
  __syncthreads();
  if (threadIdx.x == 0)
    sums[combo] = wsum[0] + wsum[1] + wsum[2] + wsum[3];
}

// Phase F: combine to the scalar loss.
__global__ void final_kernel(const int* __restrict__ counts,
                             const float* __restrict__ sums,
                             const float* __restrict__ sdfsums,
                             float* __restrict__ out) {
  if (threadIdx.x == 0 && blockIdx.x == 0) {
    float total = 0.f;
    for (int b = 0; b < NB; ++b) {
      float n1 = (float)counts[b];
      float n2 = (float)counts[NB + b];
      float mean1 = sums[b]      / fmaxf(n1, 1.f);
      float mean2 = sums[NB + b] / fmaxf(n2, 1.f);
      float cd = -mean1 + mean2;
      float ch = (n1 > 0.f && n2 > 0.f) ? fabsf(cd) : 0.f;
      total += ch + sdfsums[b] * (1.f / (float)IMG);
    }
    out[0] = total * (1.f / (float)NB);
  }
}

} // namespace

extern "C" void kernel_launch(void* const* d_in, const int* in_sizes, int n_in,
                              void* d_out, int out_size, void* d_ws, size_t ws_size,
                              hipStream_t stream) {
  const float* pred = (const float*)d_in[0];
  const float* gt   = (const float*)d_in[1];
  float* out = (float*)d_out;

  char* ws = (char*)d_ws;
  // layout (bytes):
  //   [0,32)       float sums[8]        (written by reduce)
  //   [32,48)      float sdfsums[4]     (atomic accum, zeroed each call)
  //   [64,96)      int counts[8]
  //   [128,  +16320)   int bCounts[8*510]
  //   [16448,+16320)   int bOffs[8*510]
  //   [32768,+524288)  float2 pts[8*8192]
  //   [557056,+262144) uint minq[8*8192] (init 0x7F7F7F7F each call)
  float*        sums    = (float*)(ws + 0);
  float*        sdfsums = (float*)(ws + 32);
  int*          counts  = (int*)(ws + 64);
  int*          bCounts = (int*)(ws + 128);
  int*          bOffs   = (int*)(ws + 16448);
  float2*       pts     = (float2*)(ws + 32768);
  unsigned int* minq    = (unsigned int*)(ws + 557056);

  hipMemsetAsync(ws, 0, 48, stream);                        // sums + sdfsums
  hipMemsetAsync(minq, 0x7F, NIMG * PMAX * 4, stream);      // ~3.39e38 floats

  dim3 gc(NCB, NIMG);
  count_kernel<<<gc, CB, 0, stream>>>(pred, gt, bCounts, sdfsums);
  scan_kernel<<<NIMG, 512, 0, stream>>>(bCounts, bOffs, counts);
  write_kernel<<<gc, CB, 0, stream>>>(pred, gt, bOffs, pts);
  chamfer_kernel<<<dim3(PMAX / 256, TCH, NIMG), 256, 0, stream>>>(pts, counts, minq);
  reduce_kernel<<<NIMG, 256, 0, stream>>>(minq, counts, sums);
  final_kernel<<<1, 1, 0, stream>>>(counts, sums, sdfsums, out);
}

// Round 3
// 31.592 us; speedup vs baseline: 3.3127x; 1.5298x over previous
//
#include <hip/hip_runtime.h>

namespace {

constexpr int Hh   = 256;
constexpr int Ww   = 256;
constexpr int IMG  = Hh * Ww;            // 65536
constexpr int NV   = (Hh - 1) * Ww;      // 65280 vertical candidates
constexpr int NC   = NV + Hh * (Ww - 1); // 130560 total candidates
constexpr int PMAX = 8192;
constexpr int CB   = 256;                // candidate block
constexpr int NCB  = (NC + CB - 1) / CB; // 510
constexpr int NB   = 4;                  // batch
constexpr int NIMG = 2 * NB;             // 8 images (pred 0..3, gt 4..7)
constexpr float EPSF = 1e-8f;
constexpr int TCH  = 8;                  // chamfer target chunks
constexpr int CHK  = PMAX / TCH;         // 1024 max targets per chunk (8 KB LDS)

// Candidate c -> (point, valid). Order matches reference: vertical block
// (row-major over (H-1)xW) then horizontal block (row-major over Hx(W-1)).
__device__ inline bool cand_pt(const float* img, int c, float2& pt) {
  if (c < NV) {
    int i = c >> 8, j = c & 255;             // W == 256
    float v1 = img[i * Ww + j];
    float v2 = img[(i + 1) * Ww + j];
    bool valid = (v1 == 0.f) | (v2 == 0.f) | (v1 * v2 < 0.f);
    float a = fabsf(v1) / (fabsf(v1) + fabsf(v2) + EPSF);
    float row = (v1 == 0.f) ? (float)i
              : ((v2 == 0.f) ? (float)(i + 1) : (float)i + a);
    pt.x = row; pt.y = (float)j;
    return valid;
  } else {
    int cc = c - NV;
    int i = cc / (Ww - 1);
    int j = cc - i * (Ww - 1);
    float h1 = img[i * Ww + j];
    float h2 = img[i * Ww + j + 1];
    bool valid = (h1 == 0.f) | (h2 == 0.f) | (h1 * h2 < 0.f);
    float a = fabsf(h1) / (fabsf(h1) + fabsf(h2) + EPSF);
    float col = (h1 == 0.f) ? (float)j
              : ((h2 == 0.f) ? (float)(j + 1) : (float)j + a);
    pt.x = (float)i; pt.y = col;
    return valid;
  }
}

__device__ inline const float* img_ptr(const float* pred, const float* gt, int img) {
  return (img < NB) ? pred + img * IMG : gt + (img - NB) * IMG;
}

// Phase A: per-block valid counts, fused with (a) minq init (blocks < 32 per
// image cover 8192 entries each) and (b) L1 |pred-gt| per-block partials.
__global__ void count_kernel(const float* __restrict__ pred,
                             const float* __restrict__ gt,
                             int* __restrict__ bCounts,
                             float* __restrict__ l1part,
                             unsigned int* __restrict__ minq) {
  int img = blockIdx.y;
  const float* im = img_ptr(pred, gt, img);
  int c = blockIdx.x * CB + threadIdx.x;

  // fused: re-init minq (combo index space == img index space, 8*8192)
  if (blockIdx.x < PMAX / CB)
    minq[img * PMAX + c] = 0x7F7F7F7Fu;          // ~3.39e38 as float

  bool valid = false;
  float2 pt;
  if (c < NC) valid = cand_pt(im, c, pt);
  unsigned long long b = __ballot(valid);
  __shared__ float wred[CB / 64];
  int lane = threadIdx.x & 63, wid = threadIdx.x >> 6;
  if (lane == 0) wred[wid] = (float)__popcll(b);
  __syncthreads();
  if (threadIdx.x == 0) {
    int s = 0;
    for (int w = 0; w < CB / 64; ++w) s += (int)wred[w];
    bCounts[img * NCB + blockIdx.x] = s;
  }

  // fused L1 partials (pred images only; pixel blocks only)
  if (img < NB && blockIdx.x < IMG / CB) {
    __syncthreads();
    float v = fabsf(pred[img * IMG + c] - gt[img * IMG + c]);
    for (int off = 32; off > 0; off >>= 1) v += __shfl_down(v, off, 64);
    if (lane == 0) wred[wid] = v;
    __syncthreads();
    if (threadIdx.x == 0)
      l1part[img * (IMG / CB) + blockIdx.x] = wred[0] + wred[1] + wred[2] + wred[3];
  }
}

// Phase B: per-image exclusive scan of the 510 block counts (one block/image).
__global__ void scan_kernel(const int* __restrict__ bCounts,
                            int* __restrict__ bOffs,
                            int* __restrict__ counts) {
  int img = blockIdx.x;
  __shared__ int s[512];
  int t = threadIdx.x;
  int v = (t < NCB) ? bCounts[img * NCB + t] : 0;
  s[t] = v;
  __syncthreads();
  for (int off = 1; off < 512; off <<= 1) {
    int x = s[t];
    int y = (t >= off) ? s[t - off] : 0;
    __syncthreads();
    s[t] = x + y;
    __syncthreads();
  }
  if (t < NCB) bOffs[img * NCB + t] = s[t] - v;   // exclusive prefix
  if (t == 511) counts[img] = min(s[511], PMAX);  // n = min(valid, 8192)
}

// Phase C: order-preserving compaction into pts[img][rank], rank < PMAX.
__global__ void write_kernel(const float* __restrict__ pred,
                             const float* __restrict__ gt,
                             const int* __restrict__ bOffs,
                             float2* __restrict__ pts) {
  int img = blockIdx.y;
  const float* im = img_ptr(pred, gt, img);
  int c = blockIdx.x * CB + threadIdx.x;
  bool valid = false;
  float2 pt;
  if (c < NC) valid = cand_pt(im, c, pt);
  unsigned long long b = __ballot(valid);
  __shared__ int wofs[CB / 64];
  int lane = threadIdx.x & 63, wid = threadIdx.x >> 6;
  if (lane == 0) wofs[wid] = __popcll(b);
  __syncthreads();
  if (threadIdx.x == 0) {
    int run = 0;
    for (int w = 0; w < CB / 64; ++w) { int t = wofs[w]; wofs[w] = run; run += t; }
  }
  __syncthreads();
  if (valid) {
    int rank = bOffs[img * NCB + blockIdx.x] + wofs[wid]
             + __popcll(b & ((1ull << lane) - 1ull));
    if (rank < PMAX) pts[img * PMAX + rank] = pt;
  }
}

__device__ inline void min_step(float2 p, float2 t, float& m) {
  float dx = p.x - t.x;
  float dy = p.y - t.y;
  m = fminf(m, dx * dx + dy * dy);
}

// Phase D: partial chamfer. grid = (PMAX/256 qblocks, TCH tchunks, 2*NB).
// Each block: partial min^2 over its target chunk for its 256 queries,
// merged via uint atomicMin (valid: d2 >= 0 so IEEE bits are monotone).
__global__ void chamfer_kernel(const float2* __restrict__ pts,
                               const int* __restrict__ counts,
                               unsigned int* __restrict__ minq) {
  int b   = blockIdx.z & (NB - 1);
  int dir = blockIdx.z / NB;
  int qimg = (dir == 0) ? b : NB + b;
  int timg = (dir == 0) ? NB + b : b;
  int nq = counts[qimg], nt = counts[timg];
  if (nq == 0 || nt == 0) return;                  // block-uniform
  int qbase = blockIdx.x * 256;
  if (qbase >= nq) return;
  int len = (nt + TCH - 1) / TCH;
  int ts  = blockIdx.y * len;
  if (ts >= nt) return;
  int cnt = min(len, nt - ts);

  __shared__ float2 tgt[CHK];
  for (int t = threadIdx.x; t < cnt; t += 256)
    tgt[t] = pts[timg * PMAX + ts + t];
  __syncthreads();

  int q = qbase + threadIdx.x;
  float2 p = (q < nq) ? pts[qimg * PMAX + q] : make_float2(0.f, 0.f);
  float m0 = 3.4e38f, m1 = 3.4e38f, m2 = 3.4e38f, m3 = 3.4e38f;
  int j = 0;
  for (; j + 4 <= cnt; j += 4) {                   // 4 independent min chains
    min_step(p, tgt[j + 0], m0);
    min_step(p, tgt[j + 1], m1);
    min_step(p, tgt[j + 2], m2);
    min_step(p, tgt[j + 3], m3);
  }
  for (; j < cnt; ++j) min_step(p, tgt[j], m0);
  float m = fminf(fminf(m0, m1), fminf(m2, m3));

  if (q < nq)
    atomicMin(&minq[(dir * NB + b) * PMAX + q], __float_as_uint(m));
}

// Phase E: blocks 0..7: per-(dir,b) sum sqrt(min^2) -> sums[combo].
//          blocks 8..11: reduce L1 partials -> sdfsums[b].
__global__ void reduce_kernel(const unsigned int* __restrict__ minq,
                              const int* __restrict__ counts,
                              const float* __restrict__ l1part,
                              float* __restrict__ sums,
                              float* __restrict__ sdfsums) {
  __shared__ float wsum[4];
  int lane = threadIdx.x & 63, wid = threadIdx.x >> 6;
  if (blockIdx.x < NIMG) {
    int combo = blockIdx.x;               // dir*NB + b
    int dir = combo / NB, b = combo & (NB - 1);
    int qimg = (dir == 0) ? b : NB + b;
    int nq = counts[qimg];
    float s = 0.f;
    for (int q = threadIdx.x; q < nq; q += 256)
      s += sqrtf(__uint_as_float(minq[combo * PMAX + q]));
    for (int off = 32; off > 0; off >>= 1) s += __shfl_down(s, off, 64);
    if (lane == 0) wsum[wid] = s;
    __syncthreads();
    if (threadIdx.x == 0)
      sums[combo] = wsum[0] + wsum[1] + wsum[2] + wsum[3];
  } else {
    int b = blockIdx.x - NIMG;            // 0..NB-1
    float s = l1part[b * (IMG / CB) + threadIdx.x];  // 256 partials, 256 threads
    for (int off = 32; off > 0; off >>= 1) s += __shfl_down(s, off, 64);
    if (lane == 0) wsum[wid] = s;
    __syncthreads();
    if (threadIdx.x == 0)
      sdfsums[b] = wsum[0] + wsum[1] + wsum[2] + wsum[3];
  }
}

// Phase F: combine to the scalar loss.
__global__ void final_kernel(const int* __restrict__ counts,
                             const float* __restrict__ sums,
                             const float* __restrict__ sdfsums,
                             float* __restrict__ out) {
  if (threadIdx.x == 0 && blockIdx.x == 0) {
    float total = 0.f;
    for (int b = 0; b < NB; ++b) {
      float n1 = (float)counts[b];
      float n2 = (float)counts[NB + b];
      float mean1 = sums[b]      / fmaxf(n1, 1.f);
      float mean2 = sums[NB + b] / fmaxf(n2, 1.f);
      float cd = -mean1 + mean2;
      float ch = (n1 > 0.f && n2 > 0.f) ? fabsf(cd) : 0.f;
      total += ch + sdfsums[b] * (1.f / (float)IMG);
    }
    out[0] = total * (1.f / (float)NB);
  }
}

} // namespace

extern "C" void kernel_launch(void* const* d_in, const int* in_sizes, int n_in,
                              void* d_out, int out_size, void* d_ws, size_t ws_size,
                              hipStream_t stream) {
  const float* pred = (const float*)d_in[0];
  const float* gt   = (const float*)d_in[1];
  float* out = (float*)d_out;

  char* ws = (char*)d_ws;
  // layout (bytes):
  //   [0,32)       float sums[8]        (written by reduce, no init needed)
  //   [32,48)      float sdfsums[4]     (written by reduce, no init needed)
  //   [64,96)      int counts[8]
  //   [128,  +16320)   int bCounts[8*510]
  //   [16448,+16320)   int bOffs[8*510]
  //   [32768,+524288)  float2 pts[8*8192]
  //   [557056,+262144) uint minq[8*8192]   (re-init in count_kernel)
  //   [819200,+4096)   float l1part[4*256]
  float*        sums    = (float*)(ws + 0);
  float*        sdfsums = (float*)(ws + 32);
  int*          counts  = (int*)(ws + 64);
  int*          bCounts = (int*)(ws + 128);
  int*          bOffs   = (int*)(ws + 16448);
  float2*       pts     = (float2*)(ws + 32768);
  unsigned int* minq    = (unsigned int*)(ws + 557056);
  float*        l1part  = (float*)(ws + 819200);

  dim3 gc(NCB, NIMG);
  count_kernel<<<gc, CB, 0, stream>>>(pred, gt, bCounts, l1part, minq);
  scan_kernel<<<NIMG, 512, 0, stream>>>(bCounts, bOffs, counts);
  write_kernel<<<gc, CB, 0, stream>>>(pred, gt, bOffs, pts);
  chamfer_kernel<<<dim3(PMAX / 256, TCH, NIMG), 256, 0, stream>>>(pts, counts, minq);
  reduce_kernel<<<NIMG + NB, 256, 0, stream>>>(minq, counts, l1part, sums, sdfsums);
  final_kernel<<<1, 1, 0, stream>>>(counts, sums, sdfsums, out);
}